// Round 1
// baseline (117.180 us; speedup 1.0000x reference)
//
#include <hip/hip_runtime.h>
#include <hip/hip_bf16.h>

typedef short bf16x8 __attribute__((ext_vector_type(8)));
typedef float f32x4 __attribute__((ext_vector_type(4)));

#define B_   64
#define NQ   32
#define ND   256
#define DIM  128
#define NEG_INF_F (-1.0e9f)
#define VALID_F   (-1.0e8f)

// ---------------- Kernel 1: L2-normalize rows, apply mask, emit bf16 ----------------
// One 64-lane wave per row of 128 floats. 2048 q-rows then 16384 d-rows.
__global__ __launch_bounds__(256) void normalize_rows(
    const float* __restrict__ q, const int* __restrict__ qmask,
    const float* __restrict__ d, const int* __restrict__ dmask,
    __hip_bfloat16* __restrict__ qn, __hip_bfloat16* __restrict__ dn)
{
    const int l   = threadIdx.x & 63;
    const int row = blockIdx.x * 4 + (threadIdx.x >> 6);   // 0 .. 18431

    const float* src;
    __hip_bfloat16* dst;
    int m;
    if (row < B_ * NQ) {
        src = q + row * DIM;  dst = qn + row * DIM;  m = qmask[row];
    } else {
        const int r2 = row - B_ * NQ;
        src = d + r2 * DIM;   dst = dn + r2 * DIM;   m = dmask[r2];
    }

    const float2 v = *reinterpret_cast<const float2*>(src + l * 2);
    float ss = v.x * v.x + v.y * v.y;
    #pragma unroll
    for (int off = 1; off <= 32; off <<= 1) ss += __shfl_xor(ss, off);

    const float scale = m ? (1.0f / fmaxf(sqrtf(ss), 1e-12f)) : 0.0f;

    __hip_bfloat162 o;
    o.x = __float2bfloat16(v.x * scale);
    o.y = __float2bfloat16(v.y * scale);
    *reinterpret_cast<__hip_bfloat162*>(dst + l * 2) = o;
}

// ---------------- Kernel 2: per-(bq,bd) 32x256 MFMA tile + chamfer reductions --------
// Block = 4 waves; wave w owns doc tokens [w*64, w*64+64).
// MFMA 16x16x32 bf16: A lane row = l&15, k = (l>>4)*8 + j (contiguous 8)
//                     C/D: col = l&15, row = (l>>4)*4 + reg   [m89-verified]
// NOTE the reference's mask broadcast quirk: pair (bq,bd) is gated by
// qm[bq,t] && dm[bq,s]  (doc mask indexed by the QUERY batch), while doc
// embeddings themselves are zeroed by dm[bd,s] in kernel 1.
__global__ __launch_bounds__(256) void chamfer_main(
    const __hip_bfloat16* __restrict__ qn,
    const __hip_bfloat16* __restrict__ dn,
    const int* __restrict__ qmask,
    const int* __restrict__ dmask,
    float* __restrict__ out)
{
    const int bq = blockIdx.x >> 6;
    const int bd = blockIdx.x & 63;
    const int tid = threadIdx.x;
    const int w  = tid >> 6;
    const int l  = tid & 63;
    const int lr = l & 15;
    const int lk = l >> 4;

    const __hip_bfloat16* Q  = qn + bq * (NQ * DIM);
    const __hip_bfloat16* Dp = dn + (bd * ND + w * 64) * DIM;

    f32x4 acc[2][4] = {};

    #pragma unroll
    for (int kk = 0; kk < 4; ++kk) {
        const int k0 = kk * 32 + lk * 8;
        const bf16x8 a0 = *reinterpret_cast<const bf16x8*>(Q + lr * DIM + k0);
        const bf16x8 a1 = *reinterpret_cast<const bf16x8*>(Q + (16 + lr) * DIM + k0);
        bf16x8 bfr[4];
        #pragma unroll
        for (int ni = 0; ni < 4; ++ni)
            bfr[ni] = *reinterpret_cast<const bf16x8*>(Dp + (ni * 16 + lr) * DIM + k0);
        #pragma unroll
        for (int ni = 0; ni < 4; ++ni) {
            acc[0][ni] = __builtin_amdgcn_mfma_f32_16x16x32_bf16(a0, bfr[ni], acc[0][ni], 0, 0, 0);
            acc[1][ni] = __builtin_amdgcn_mfma_f32_16x16x32_bf16(a1, bfr[ni], acc[1][ni], 0, 0, 0);
        }
    }

    // ---- masks (doc mask indexed by bq — reference broadcast quirk) ----
    int qmv[2][4];
    #pragma unroll
    for (int mi = 0; mi < 2; ++mi)
        #pragma unroll
        for (int r = 0; r < 4; ++r)
            qmv[mi][r] = qmask[bq * NQ + mi * 16 + lk * 4 + r];
    int dmv[4];
    #pragma unroll
    for (int ni = 0; ni < 4; ++ni)
        dmv[ni] = dmask[bq * ND + w * 64 + ni * 16 + lr];

    // ---- masked values + in-lane partial maxes ----
    float rmax[2][4];   // per owned row, max over this lane's 4 columns
    float cmax[4];      // per owned column, max over this lane's 8 rows
    #pragma unroll
    for (int ni = 0; ni < 4; ++ni) cmax[ni] = NEG_INF_F;
    #pragma unroll
    for (int mi = 0; mi < 2; ++mi) {
        #pragma unroll
        for (int r = 0; r < 4; ++r) {
            float rm = NEG_INF_F;
            #pragma unroll
            for (int ni = 0; ni < 4; ++ni) {
                const float v = (qmv[mi][r] && dmv[ni]) ? acc[mi][ni][r] : NEG_INF_F;
                rm = fmaxf(rm, v);
                cmax[ni] = fmaxf(cmax[ni], v);
            }
            rmax[mi][r] = rm;
        }
    }

    // ---- d2q: column max over all 32 rows (combine lanes differing in lk) ----
    #pragma unroll
    for (int ni = 0; ni < 4; ++ni) {
        cmax[ni] = fmaxf(cmax[ni], __shfl_xor(cmax[ni], 16));
        cmax[ni] = fmaxf(cmax[ni], __shfl_xor(cmax[ni], 32));
    }
    float sd = 0.0f, cd = 0.0f;
    if (lk == 0) {   // one copy per column
        #pragma unroll
        for (int ni = 0; ni < 4; ++ni)
            if (cmax[ni] > VALID_F) { sd += cmax[ni]; cd += 1.0f; }
    }
    #pragma unroll
    for (int off = 1; off <= 32; off <<= 1) {
        sd += __shfl_xor(sd, off);
        cd += __shfl_xor(cd, off);
    }

    __shared__ float s_rmax[4][NQ];
    __shared__ float s_sd[4], s_cd[4];
    if (l == 0) { s_sd[w] = sd; s_cd[w] = cd; }

    // ---- q2d partial: row max over this wave's 64 columns (combine lanes differing in lr) ----
    #pragma unroll
    for (int mi = 0; mi < 2; ++mi) {
        #pragma unroll
        for (int r = 0; r < 4; ++r) {
            #pragma unroll
            for (int off = 1; off <= 8; off <<= 1)
                rmax[mi][r] = fmaxf(rmax[mi][r], __shfl_xor(rmax[mi][r], off));
        }
    }
    if (lr == 0) {   // lanes 0,16,32,48 → 8 rows each
        #pragma unroll
        for (int mi = 0; mi < 2; ++mi)
            #pragma unroll
            for (int r = 0; r < 4; ++r)
                s_rmax[w][mi * 16 + lk * 4 + r] = rmax[mi][r];
    }
    __syncthreads();

    // ---- final combine (wave 0) ----
    if (w == 0) {
        float v = NEG_INF_F;
        if (l < NQ) {
            #pragma unroll
            for (int wv = 0; wv < 4; ++wv) v = fmaxf(v, s_rmax[wv][l]);
        }
        float sq = 0.0f, cq = 0.0f;
        if (l < NQ && v > VALID_F) { sq = v; cq = 1.0f; }
        #pragma unroll
        for (int off = 1; off <= 32; off <<= 1) {
            sq += __shfl_xor(sq, off);
            cq += __shfl_xor(cq, off);
        }
        if (l == 0) {
            const float q2d = sq / fmaxf(cq, 1.0f);
            const float sdt = s_sd[0] + s_sd[1] + s_sd[2] + s_sd[3];
            const float cdt = s_cd[0] + s_cd[1] + s_cd[2] + s_cd[3];
            const float d2q = sdt / fmaxf(cdt, 1.0f);
            out[bq * B_ + bd] = 0.5f * (q2d + d2q);
        }
    }
}

extern "C" void kernel_launch(void* const* d_in, const int* in_sizes, int n_in,
                              void* d_out, int out_size, void* d_ws, size_t ws_size,
                              hipStream_t stream) {
    const float* q  = (const float*)d_in[0];   // [64][32][128] f32
    const int*   qm = (const int*)d_in[1];     // [64][32] i32
    const float* d  = (const float*)d_in[2];   // [64][256][128] f32
    const int*   dm = (const int*)d_in[3];     // [64][256] i32
    float* out = (float*)d_out;                // [64][64] f32

    __hip_bfloat16* qn = (__hip_bfloat16*)d_ws;          // 2048*128 bf16 = 512 KB
    __hip_bfloat16* dn = qn + (B_ * NQ) * DIM;           // 16384*128 bf16 = 4 MB

    // 18432 rows total, 4 waves (rows) per 256-thread block
    normalize_rows<<<(B_ * NQ + B_ * ND) / 4, 256, 0, stream>>>(q, qm, d, dm, qn, dn);
    chamfer_main<<<B_ * B_, 256, 0, stream>>>(qn, dn, qm, dm, out);
}

// Round 2
// 115.514 us; speedup vs baseline: 1.0144x; 1.0144x over previous
//
#include <hip/hip_runtime.h>
#include <hip/hip_bf16.h>

typedef short bf16x8 __attribute__((ext_vector_type(8)));
typedef short short8 __attribute__((ext_vector_type(8)));
typedef float f32x4 __attribute__((ext_vector_type(4)));

#define B_   64
#define NQ   32
#define ND   256
#define DIM  128
#define MT   4          // bq values per chamfer block
#define NEG_INF_F (-1.0e9f)
#define VALID_F   (-1.0e8f)

// ---------------- Kernel 1: L2-normalize rows, apply mask, emit bf16 ----------------
// 16 lanes per row (float4 x2 loads, 4-step shuffle reduce), 16 rows per 256-thr block.
__global__ __launch_bounds__(256) void normalize_rows(
    const float* __restrict__ q, const int* __restrict__ qmask,
    const float* __restrict__ d, const int* __restrict__ dmask,
    __hip_bfloat16* __restrict__ qn, __hip_bfloat16* __restrict__ dn)
{
    const int tid  = threadIdx.x;
    const int sub  = tid & 15;               // lane within row
    const int row  = blockIdx.x * 16 + (tid >> 4);   // 0 .. 18431

    const float* src;
    __hip_bfloat16* dst;
    int m;
    if (row < B_ * NQ) {
        src = q + row * DIM;  dst = qn + row * DIM;  m = qmask[row];
    } else {
        const int r2 = row - B_ * NQ;
        src = d + r2 * DIM;   dst = dn + r2 * DIM;   m = dmask[r2];
    }

    const float4 v0 = *reinterpret_cast<const float4*>(src + sub * 8);
    const float4 v1 = *reinterpret_cast<const float4*>(src + sub * 8 + 4);
    float ss = v0.x*v0.x + v0.y*v0.y + v0.z*v0.z + v0.w*v0.w
             + v1.x*v1.x + v1.y*v1.y + v1.z*v1.z + v1.w*v1.w;
    #pragma unroll
    for (int off = 1; off <= 8; off <<= 1) ss += __shfl_xor(ss, off);

    const float scale = m ? (1.0f / fmaxf(sqrtf(ss), 1e-12f)) : 0.0f;

    short8 o;
    const float f[8] = {v0.x, v0.y, v0.z, v0.w, v1.x, v1.y, v1.z, v1.w};
    #pragma unroll
    for (int j = 0; j < 8; ++j) {
        __hip_bfloat16 b = __float2bfloat16(f[j] * scale);
        o[j] = *reinterpret_cast<short*>(&b);
    }
    *reinterpret_cast<short8*>(dst + sub * 8) = o;
}

// ---------------- Kernel 2: per-(4 bq, bd) MFMA tile + chamfer reductions --------
// Block = 4 waves; wave w owns doc tokens [w*64, w*64+64) for ALL 4 bq.
// MFMA 16x16x32 bf16: A lane row = l&15, k = (l>>4)*8 + j (contiguous 8)
//                     C/D: col = l&15, row = (l>>4)*4 + reg   [m89-verified]
// Reference mask-broadcast quirk: pair (bq,bd) is gated by qm[bq,t] && dm[bq,s]
// (doc mask indexed by the QUERY batch); doc embeddings zeroed by dm[bd,s] in k1.
__global__ __launch_bounds__(256) void chamfer_main(
    const __hip_bfloat16* __restrict__ qn,
    const __hip_bfloat16* __restrict__ dn,
    const int* __restrict__ qmask,
    const int* __restrict__ dmask,
    float* __restrict__ out)
{
    const int bq0 = (blockIdx.x >> 6) * MT;
    const int bd  = blockIdx.x & 63;
    const int tid = threadIdx.x;
    const int w   = tid >> 6;
    const int l   = tid & 63;
    const int lr  = l & 15;
    const int lk  = l >> 4;

    const __hip_bfloat16* Dp = dn + (bd * ND + w * 64) * DIM;

    f32x4 acc[MT][2][4] = {};

    #pragma unroll
    for (int kk = 0; kk < 4; ++kk) {
        const int k0 = kk * 32 + lk * 8;
        bf16x8 bfr[4];
        #pragma unroll
        for (int ni = 0; ni < 4; ++ni)
            bfr[ni] = *reinterpret_cast<const bf16x8*>(Dp + (ni * 16 + lr) * DIM + k0);
        #pragma unroll
        for (int m = 0; m < MT; ++m) {
            const __hip_bfloat16* Q = qn + (bq0 + m) * (NQ * DIM);
            const bf16x8 a0 = *reinterpret_cast<const bf16x8*>(Q + lr * DIM + k0);
            const bf16x8 a1 = *reinterpret_cast<const bf16x8*>(Q + (16 + lr) * DIM + k0);
            #pragma unroll
            for (int ni = 0; ni < 4; ++ni) {
                acc[m][0][ni] = __builtin_amdgcn_mfma_f32_16x16x32_bf16(a0, bfr[ni], acc[m][0][ni], 0, 0, 0);
                acc[m][1][ni] = __builtin_amdgcn_mfma_f32_16x16x32_bf16(a1, bfr[ni], acc[m][1][ni], 0, 0, 0);
            }
        }
    }

    __shared__ float s_rmax[4][MT][NQ];
    __shared__ float s_sd[4][MT], s_cd[4][MT];

    #pragma unroll
    for (int m = 0; m < MT; ++m) {
        const int bq = bq0 + m;
        // masks (doc mask indexed by bq — reference broadcast quirk)
        int qmv[2][4];
        #pragma unroll
        for (int mi = 0; mi < 2; ++mi)
            #pragma unroll
            for (int r = 0; r < 4; ++r)
                qmv[mi][r] = qmask[bq * NQ + mi * 16 + lk * 4 + r];
        int dmv[4];
        #pragma unroll
        for (int ni = 0; ni < 4; ++ni)
            dmv[ni] = dmask[bq * ND + w * 64 + ni * 16 + lr];

        float rmax[2][4];
        float cmax[4];
        #pragma unroll
        for (int ni = 0; ni < 4; ++ni) cmax[ni] = NEG_INF_F;
        #pragma unroll
        for (int mi = 0; mi < 2; ++mi) {
            #pragma unroll
            for (int r = 0; r < 4; ++r) {
                float rm = NEG_INF_F;
                #pragma unroll
                for (int ni = 0; ni < 4; ++ni) {
                    const float v = (qmv[mi][r] && dmv[ni]) ? acc[m][mi][ni][r] : NEG_INF_F;
                    rm = fmaxf(rm, v);
                    cmax[ni] = fmaxf(cmax[ni], v);
                }
                rmax[mi][r] = rm;
            }
        }

        // d2q: column max over 32 rows (lanes differing in lk), then masked mean parts
        #pragma unroll
        for (int ni = 0; ni < 4; ++ni) {
            cmax[ni] = fmaxf(cmax[ni], __shfl_xor(cmax[ni], 16));
            cmax[ni] = fmaxf(cmax[ni], __shfl_xor(cmax[ni], 32));
        }
        float sd = 0.0f, cd = 0.0f;
        if (lk == 0) {
            #pragma unroll
            for (int ni = 0; ni < 4; ++ni)
                if (cmax[ni] > VALID_F) { sd += cmax[ni]; cd += 1.0f; }
        }
        #pragma unroll
        for (int off = 1; off <= 32; off <<= 1) {
            sd += __shfl_xor(sd, off);
            cd += __shfl_xor(cd, off);
        }
        if (l == 0) { s_sd[w][m] = sd; s_cd[w][m] = cd; }

        // q2d partial: row max over this wave's 64 columns (lanes differing in lr)
        #pragma unroll
        for (int mi = 0; mi < 2; ++mi) {
            #pragma unroll
            for (int r = 0; r < 4; ++r) {
                #pragma unroll
                for (int off = 1; off <= 8; off <<= 1)
                    rmax[mi][r] = fmaxf(rmax[mi][r], __shfl_xor(rmax[mi][r], off));
            }
        }
        if (lr == 0) {
            #pragma unroll
            for (int mi = 0; mi < 2; ++mi)
                #pragma unroll
                for (int r = 0; r < 4; ++r)
                    s_rmax[w][m][mi * 16 + lk * 4 + r] = rmax[mi][r];
        }
    }
    __syncthreads();

    // ---- final combine: wave w handles bq index m = w (fully parallel tail) ----
    {
        const int m = w;
        float v = NEG_INF_F;
        if (l < NQ) {
            #pragma unroll
            for (int wv = 0; wv < 4; ++wv) v = fmaxf(v, s_rmax[wv][m][l]);
        }
        float sq = 0.0f, cq = 0.0f;
        if (l < NQ && v > VALID_F) { sq = v; cq = 1.0f; }
        #pragma unroll
        for (int off = 1; off <= 32; off <<= 1) {
            sq += __shfl_xor(sq, off);
            cq += __shfl_xor(cq, off);
        }
        if (l == 0) {
            const float q2d = sq / fmaxf(cq, 1.0f);
            const float sdt = s_sd[0][m] + s_sd[1][m] + s_sd[2][m] + s_sd[3][m];
            const float cdt = s_cd[0][m] + s_cd[1][m] + s_cd[2][m] + s_cd[3][m];
            const float d2q = sdt / fmaxf(cdt, 1.0f);
            out[(bq0 + m) * B_ + bd] = 0.5f * (q2d + d2q);
        }
    }
}

extern "C" void kernel_launch(void* const* d_in, const int* in_sizes, int n_in,
                              void* d_out, int out_size, void* d_ws, size_t ws_size,
                              hipStream_t stream) {
    const float* q  = (const float*)d_in[0];   // [64][32][128] f32
    const int*   qm = (const int*)d_in[1];     // [64][32] i32
    const float* d  = (const float*)d_in[2];   // [64][256][128] f32
    const int*   dm = (const int*)d_in[3];     // [64][256] i32
    float* out = (float*)d_out;                // [64][64] f32

    __hip_bfloat16* qn = (__hip_bfloat16*)d_ws;          // 2048*128 bf16 = 512 KB
    __hip_bfloat16* dn = qn + (B_ * NQ) * DIM;           // 16384*128 bf16 = 4 MB

    // 18432 rows total, 16 rows per 256-thread block
    normalize_rows<<<(B_ * NQ + B_ * ND) / 16, 256, 0, stream>>>(q, qm, d, dm, qn, dn);
    chamfer_main<<<(B_ / MT) * B_, 256, 0, stream>>>(qn, dn, qm, dm, out);
}

// Round 3
// 94.593 us; speedup vs baseline: 1.2388x; 1.2212x over previous
//
#include <hip/hip_runtime.h>
#include <hip/hip_bf16.h>
#include <stdint.h>

typedef short bf16x8 __attribute__((ext_vector_type(8)));
typedef short short8 __attribute__((ext_vector_type(8)));
typedef float f32x4 __attribute__((ext_vector_type(4)));

#define B_   64
#define NQ   32
#define ND   256
#define DIM  128
#define MT   4          // bq values per chamfer block
#define NEG_INF_F (-1.0e9f)
#define VALID_F   (-1.0e8f)

// Global layout of qn/dn is PRE-SWIZZLED: 16B chunk j of row r lives at chunk
// position j ^ (r&7) within the row (m173 pattern: global pre-swizzle + linear
// global_load_lds + swizzled ds_read => conflict-free b128 LDS reads).

__device__ __forceinline__ void lds_cp16(const void* g, void* l) {
    __builtin_amdgcn_global_load_lds(
        (const __attribute__((address_space(1))) unsigned int*)g,
        (__attribute__((address_space(3))) unsigned int*)l,
        16, 0, 0);
}

// ---------------- Kernel 1: L2-normalize rows, mask, emit SWIZZLED bf16 ----------------
// 16 lanes per row; lane `sub` owns 8 consecutive cols (16B chunk j=sub) and
// stores it at chunk sub ^ (row&7).
__global__ __launch_bounds__(256) void normalize_rows(
    const float* __restrict__ q, const int* __restrict__ qmask,
    const float* __restrict__ d, const int* __restrict__ dmask,
    __hip_bfloat16* __restrict__ qn, __hip_bfloat16* __restrict__ dn)
{
    const int tid  = threadIdx.x;
    const int sub  = tid & 15;
    const int row  = blockIdx.x * 16 + (tid >> 4);   // 0 .. 18431

    const float* src;
    __hip_bfloat16* dst;
    int m, lrow;
    if (row < B_ * NQ) {
        lrow = row;
        src = q + (size_t)lrow * DIM;  dst = qn + (size_t)lrow * DIM;  m = qmask[lrow];
    } else {
        lrow = row - B_ * NQ;
        src = d + (size_t)lrow * DIM;  dst = dn + (size_t)lrow * DIM;  m = dmask[lrow];
    }

    const float4 v0 = *reinterpret_cast<const float4*>(src + sub * 8);
    const float4 v1 = *reinterpret_cast<const float4*>(src + sub * 8 + 4);
    float ss = v0.x*v0.x + v0.y*v0.y + v0.z*v0.z + v0.w*v0.w
             + v1.x*v1.x + v1.y*v1.y + v1.z*v1.z + v1.w*v1.w;
    #pragma unroll
    for (int off = 1; off <= 8; off <<= 1) ss += __shfl_xor(ss, off);

    const float scale = m ? (1.0f / fmaxf(sqrtf(ss), 1e-12f)) : 0.0f;

    short8 o;
    const float f[8] = {v0.x, v0.y, v0.z, v0.w, v1.x, v1.y, v1.z, v1.w};
    #pragma unroll
    for (int j = 0; j < 8; ++j) {
        __hip_bfloat16 b = __float2bfloat16(f[j] * scale);
        o[j] = *reinterpret_cast<short*>(&b);
    }
    const int chunk = sub ^ (lrow & 7);
    *reinterpret_cast<short8*>(dst + chunk * 8) = o;
}

// ---------------- Kernel 2: LDS-staged (4 bq, bd) MFMA tile + chamfer reductions ------
// 1 block/CU (102KB LDS). Stage D panel (64KB) + Q panel (32KB) via
// global_load_lds (no VGPR roundtrip, full MLP), then compute entirely from LDS.
// MFMA 16x16x32 bf16: A lane row=l&15, k=(l>>4)*8+j; C/D col=l&15, row=(l>>4)*4+reg.
// Mask quirk: pair (bq,bd) gated by qm[bq,t] && dm[bq,s] (doc mask via QUERY batch).
__global__ __launch_bounds__(256) void chamfer_main(
    const __hip_bfloat16* __restrict__ qn,
    const __hip_bfloat16* __restrict__ dn,
    const int* __restrict__ qmask,
    const int* __restrict__ dmask,
    float* __restrict__ out)
{
    __shared__ __hip_bfloat16 ldsD[ND * DIM];        // 64 KB
    __shared__ __hip_bfloat16 ldsQ[MT * NQ * DIM];   // 32 KB
    __shared__ float s_cmax[MT][ND];                 // 4 KB
    __shared__ float s_rmaxT[MT][NQ][4];             // 2 KB

    const int bq0 = (blockIdx.x >> 6) * MT;
    const int bd  = blockIdx.x & 63;
    const int tid = threadIdx.x;
    const int w   = tid >> 6;
    const int l   = tid & 63;
    const int lr  = l & 15;
    const int lk  = l >> 4;

    // ---- stage: wave w copies its 16KB D slice + 8KB Q slice (all issues back-to-back)
    {
        const char* gD = (const char*)(dn + (size_t)(bd * ND) * DIM) + w * 16384;
        char*       lD = (char*)&ldsD[0] + w * 16384;
        #pragma unroll
        for (int c = 0; c < 16; ++c)
            lds_cp16(gD + c * 1024 + l * 16, lD + c * 1024);
        const char* gQ = (const char*)(qn + (size_t)(bq0 * NQ) * DIM) + w * 8192;
        char*       lQ = (char*)&ldsQ[0] + w * 8192;
        #pragma unroll
        for (int c = 0; c < 8; ++c)
            lds_cp16(gQ + c * 1024 + l * 16, lQ + c * 1024);
    }

    // ---- masks into registers (overlap staging) — doc mask indexed by bq (quirk)
    int qmv[MT][2][4];
    int dmv[MT][4];
    #pragma unroll
    for (int m = 0; m < MT; ++m) {
        #pragma unroll
        for (int mi = 0; mi < 2; ++mi)
            #pragma unroll
            for (int r = 0; r < 4; ++r)
                qmv[m][mi][r] = qmask[(bq0 + m) * NQ + mi * 16 + lk * 4 + r];
        #pragma unroll
        for (int ni = 0; ni < 4; ++ni)
            dmv[m][ni] = dmask[(bq0 + m) * ND + w * 64 + ni * 16 + lr];
    }

    __syncthreads();   // drains vmcnt (global_load_lds) + lgkmcnt

    // ---- MFMA phase, entirely from LDS (swizzled reads) ----
    f32x4 acc[MT][2][4] = {};
    #pragma unroll
    for (int kk = 0; kk < 4; ++kk) {
        const int slot = (kk * 4 + lk) ^ (lr & 7);
        bf16x8 bfr[4];
        #pragma unroll
        for (int ni = 0; ni < 4; ++ni) {
            const int rowd = w * 64 + ni * 16 + lr;
            bfr[ni] = *reinterpret_cast<const bf16x8*>((const char*)&ldsD[0] + rowd * 256 + slot * 16);
        }
        #pragma unroll
        for (int m = 0; m < MT; ++m) {
            #pragma unroll
            for (int mi = 0; mi < 2; ++mi) {
                const int rowq = m * NQ + mi * 16 + lr;
                const bf16x8 a = *reinterpret_cast<const bf16x8*>((const char*)&ldsQ[0] + rowq * 256 + slot * 16);
                #pragma unroll
                for (int ni = 0; ni < 4; ++ni)
                    acc[m][mi][ni] = __builtin_amdgcn_mfma_f32_16x16x32_bf16(a, bfr[ni], acc[m][mi][ni], 0, 0, 0);
            }
        }
    }

    // ---- per-wave partial maxes → LDS (cheap: 2-step + 4-step shuffles only) ----
    #pragma unroll
    for (int m = 0; m < MT; ++m) {
        float rmax[2][4];
        float cmax[4];
        #pragma unroll
        for (int ni = 0; ni < 4; ++ni) cmax[ni] = NEG_INF_F;
        #pragma unroll
        for (int mi = 0; mi < 2; ++mi) {
            #pragma unroll
            for (int r = 0; r < 4; ++r) {
                float rm = NEG_INF_F;
                #pragma unroll
                for (int ni = 0; ni < 4; ++ni) {
                    const float v = (qmv[m][mi][r] && dmv[m][ni]) ? acc[m][mi][ni][r] : NEG_INF_F;
                    rm = fmaxf(rm, v);
                    cmax[ni] = fmaxf(cmax[ni], v);
                }
                rmax[mi][r] = rm;
            }
        }
        // column max over 32 rows (lanes differing in lk bits)
        #pragma unroll
        for (int ni = 0; ni < 4; ++ni) {
            cmax[ni] = fmaxf(cmax[ni], __shfl_xor(cmax[ni], 16));
            cmax[ni] = fmaxf(cmax[ni], __shfl_xor(cmax[ni], 32));
        }
        if (lk == 0) {
            #pragma unroll
            for (int ni = 0; ni < 4; ++ni)
                s_cmax[m][w * 64 + ni * 16 + lr] = cmax[ni];
        }
        // row max over this wave's 64 cols (lanes differing in lr bits)
        #pragma unroll
        for (int mi = 0; mi < 2; ++mi)
            #pragma unroll
            for (int r = 0; r < 4; ++r) {
                #pragma unroll
                for (int off = 1; off <= 8; off <<= 1)
                    rmax[mi][r] = fmaxf(rmax[mi][r], __shfl_xor(rmax[mi][r], off));
            }
        if (lr == 0) {
            #pragma unroll
            for (int mi = 0; mi < 2; ++mi)
                #pragma unroll
                for (int r = 0; r < 4; ++r)
                    s_rmaxT[m][mi * 16 + lk * 4 + r][w] = rmax[mi][r];
        }
    }
    __syncthreads();

    // ---- final combine: wave w finishes bq index m = w (one fused 6-step sum) ----
    {
        const int m = w;
        // d2q: lane l owns 4 doc columns
        const float4 cm = *reinterpret_cast<const float4*>(&s_cmax[m][l * 4]);
        float sd = 0.0f, cd = 0.0f;
        if (cm.x > VALID_F) { sd += cm.x; cd += 1.0f; }
        if (cm.y > VALID_F) { sd += cm.y; cd += 1.0f; }
        if (cm.z > VALID_F) { sd += cm.z; cd += 1.0f; }
        if (cm.w > VALID_F) { sd += cm.w; cd += 1.0f; }
        // q2d: lanes 0..31 own one query row each
        float sq = 0.0f, cq = 0.0f;
        if (l < NQ) {
            const float4 rm4 = *reinterpret_cast<const float4*>(&s_rmaxT[m][l][0]);
            const float v = fmaxf(fmaxf(rm4.x, rm4.y), fmaxf(rm4.z, rm4.w));
            if (v > VALID_F) { sq = v; cq = 1.0f; }
        }
        #pragma unroll
        for (int off = 1; off <= 32; off <<= 1) {
            sd += __shfl_xor(sd, off);
            cd += __shfl_xor(cd, off);
            sq += __shfl_xor(sq, off);
            cq += __shfl_xor(cq, off);
        }
        if (l == 0) {
            const float q2d = sq / fmaxf(cq, 1.0f);
            const float d2q = sd / fmaxf(cd, 1.0f);
            out[(bq0 + m) * B_ + bd] = 0.5f * (q2d + d2q);
        }
    }
}

extern "C" void kernel_launch(void* const* d_in, const int* in_sizes, int n_in,
                              void* d_out, int out_size, void* d_ws, size_t ws_size,
                              hipStream_t stream) {
    const float* q  = (const float*)d_in[0];   // [64][32][128] f32
    const int*   qm = (const int*)d_in[1];     // [64][32] i32
    const float* d  = (const float*)d_in[2];   // [64][256][128] f32
    const int*   dm = (const int*)d_in[3];     // [64][256] i32
    float* out = (float*)d_out;                // [64][64] f32

    __hip_bfloat16* qn = (__hip_bfloat16*)d_ws;          // 2048*128 bf16 = 512 KB (swizzled)
    __hip_bfloat16* dn = qn + (B_ * NQ) * DIM;           // 16384*128 bf16 = 4 MB (swizzled)

    normalize_rows<<<(B_ * NQ + B_ * ND) / 16, 256, 0, stream>>>(q, qm, d, dm, qn, dn);
    chamfer_main<<<(B_ / MT) * B_, 256, 0, stream>>>(qn, dn, qm, dm, out);
}